// Round 15
// baseline (43.690 us; speedup 1.0000x reference)
//
#include <hip/hip_runtime.h>
#include <cmath>

// Round 15: three-phase decoupled design.
//   qprep (1 block): circuit -> A[81][4] in d_ws (validated r10-r14).
//   qgemv (1024 blocks): PURE stream x->angles via swapped-operand MFMA
//     (A=W, B=x^T): C col=lane&15=x-row, row=qubit -> lanes 0..15 hold
//     float4 angles -> coalesced store into d_out. No LDS, no barriers,
//     no tail; 3-deep subtile rotation -> loads in flight continuously.
//   qtail (2048 blocks): in-place d_out: angles -> tanh/sincos ->
//     81-term contraction vs s_load'ed A -> exps.
// Rationale: fused designs cap at ~4.3 TB/s because the 1800cy tail has
// no loads outstanding (Little's law: need ~22KB/CU in flight for 6.3TB/s).
// Splitting lets qgemv saturate HBM and qtail run at VALU speed.

typedef __attribute__((ext_vector_type(8))) short bf16x8;
typedef __attribute__((ext_vector_type(4))) float f32x4;

__device__ __forceinline__ short f2bf(float f) {
  const unsigned u = __float_as_uint(f);
  return (short)((u + 0x7FFF + ((u >> 16) & 1)) >> 16);   // RNE
}

// ---- prep kernel: verbatim round-10 (validated rounds 10-14) ----
__global__ __launch_bounds__(256) void qprep_kernel(
    const float* __restrict__ qw,   // [3][4][2]
    float* __restrict__ A_out)      // [81][4]
{
  __shared__ float sre[16][17];
  __shared__ float sim[16][17];
  __shared__ float M[4][16][16];
  const int tid = threadIdx.x;
  const int col = tid >> 4;
  const int u   = tid & 15;

  sre[col][u] = (u == col) ? 1.0f : 0.0f;
  sim[col][u] = 0.0f;
  __syncthreads();

#pragma unroll
  for (int l = 0; l < 3; ++l) {
#pragma unroll
    for (int w = 0; w < 4; ++w) {
      const int mask = 8 >> w;     // wire 0 = MSB
      float sh, ch, sh2, ch2;
      __sincosf(0.5f * qw[(l * 4 + w) * 2 + 0], &sh, &ch);    // RY
      __sincosf(0.5f * qw[(l * 4 + w) * 2 + 1], &sh2, &ch2);  // RZ
      const int ua = u & ~mask, ub = u | mask;
      const float ar = sre[col][ua], ai = sim[col][ua];
      const float br = sre[col][ub], bi = sim[col][ub];
      __syncthreads();
      float nr, ni;
      if (u & mask) { nr = sh * ar + ch * br; ni = sh * ai + ch * bi; }
      else          { nr = ch * ar - sh * br; ni = ch * ai - sh * bi; }
      float rr, ri;
      if (u & mask) { rr = ch2 * nr - sh2 * ni; ri = ch2 * ni + sh2 * nr; }
      else          { rr = ch2 * nr + sh2 * ni; ri = ch2 * ni - sh2 * nr; }
      sre[col][u] = rr; sim[col][u] = ri;
      __syncthreads();
    }
    int src = u;
    if (src & 1) src ^= 8;
    if (src & 2) src ^= 1;
    if (src & 4) src ^= 2;
    if (src & 8) src ^= 4;
    const float pr = sre[col][src], pi = sim[col][src];
    __syncthreads();
    sre[col][u] = pr; sim[col][u] = pi;
    __syncthreads();
  }

  for (int idx = tid; idx < 1024; idx += 256) {
    const int w = idx >> 8, s = (idx >> 4) & 15, t = idx & 15;
    const int mask = 8 >> w;
    float acc = 0.0f;
#pragma unroll
    for (int uu = 0; uu < 16; ++uu) {
      const float z = (uu & mask) ? -1.0f : 1.0f;
      acc += z * (sre[s][uu] * sre[t][uu] + sim[s][uu] * sim[t][uu]);
    }
    M[w][s][t] = acc;
  }
  __syncthreads();

  for (int idx = tid; idx < 324; idx += 256) {
    const int w = idx & 3, pq = idx >> 2;
    const int p = pq / 9, q = pq % 9;
    const int i0 = p / 3, i1 = p % 3, i2 = q / 3, i3 = q % 3;
    float acc = 0.0f;
#pragma unroll
    for (int comb = 0; comb < 16; ++comb) {
      int s = 0, t = 0;
      float coef = 0.0625f;
      int j;
      j = (comb >> 3) & 1; s |= j << 3; t |= ((i0 == 2) ? (j ^ 1) : j) << 3; if (i0 == 1 && j) coef = -coef;
      j = (comb >> 2) & 1; s |= j << 2; t |= ((i1 == 2) ? (j ^ 1) : j) << 2; if (i1 == 1 && j) coef = -coef;
      j = (comb >> 1) & 1; s |= j << 1; t |= ((i2 == 2) ? (j ^ 1) : j) << 1; if (i2 == 1 && j) coef = -coef;
      j = comb & 1;        s |= j;      t |= ((i3 == 2) ? (j ^ 1) : j);      if (i3 == 1 && j) coef = -coef;
      acc = fmaf(coef, M[w][s][t], acc);
    }
    A_out[idx] = acc;   // layout [pq*4 + w]
  }
}

// load subtile S (16 rows) fragment into 4 named float4 regs
#define LDSUB(V0, V1, V2, V3, S) {                                          \
  const float* rp_ = x + (wrow0 + (size_t)((S) * 16 + arow)) * 64 + kgrp * 8;\
  V0 = *reinterpret_cast<const float4*>(rp_);                               \
  V1 = *reinterpret_cast<const float4*>(rp_ + 4);                           \
  V2 = *reinterpret_cast<const float4*>(rp_ + 32);                          \
  V3 = *reinterpret_cast<const float4*>(rp_ + 36); }

// cvt + 2x MFMA (A=W, B=x^T) + coalesced angle store from lanes 0..15
#define MFST(V0, V1, V2, V3, S) {                                           \
  bf16x8 xf0_, xf1_;                                                        \
  xf0_[0] = f2bf(V0.x); xf0_[1] = f2bf(V0.y); xf0_[2] = f2bf(V0.z);         \
  xf0_[3] = f2bf(V0.w); xf0_[4] = f2bf(V1.x); xf0_[5] = f2bf(V1.y);         \
  xf0_[6] = f2bf(V1.z); xf0_[7] = f2bf(V1.w);                               \
  xf1_[0] = f2bf(V2.x); xf1_[1] = f2bf(V2.y); xf1_[2] = f2bf(V2.z);         \
  xf1_[3] = f2bf(V2.w); xf1_[4] = f2bf(V3.x); xf1_[5] = f2bf(V3.y);         \
  xf1_[6] = f2bf(V3.z); xf1_[7] = f2bf(V3.w);                               \
  f32x4 acc_ = __builtin_amdgcn_mfma_f32_16x16x32_bf16(wf0, xf0_, zero, 0, 0, 0); \
  acc_ = __builtin_amdgcn_mfma_f32_16x16x32_bf16(wf1, xf1_, acc_, 0, 0, 0); \
  if (lane < 16)                                                            \
    reinterpret_cast<float4*>(ang)[wrow0 + (S) * 16 + lane] =               \
        make_float4(acc_[0], acc_[1], acc_[2], acc_[3]); }

// ---- phase 1: pure-stream GEMV, angles -> d_out ----
__global__ __launch_bounds__(256)
__attribute__((amdgpu_waves_per_eu(4, 8)))
void qgemv_kernel(
    const float* __restrict__ x,    // [B][64]
    const float* __restrict__ Wp,   // [4][64]
    float* __restrict__ ang)        // [B][4]  (= d_out)
{
  const int tid  = threadIdx.x;
  const int lane = tid & 63;
  const int wid  = tid >> 6;
  const int arow = lane & 15;        // x-row within subtile (B-frag col)
  const int kgrp = lane >> 4;        // k-group
  const size_t wrow0 = ((size_t)blockIdx.x * 4 + wid) * 128;  // 8 subtiles

  // A-frag: W, rows (lane&15) = qubit 0..3 real, 4..15 zero
  bf16x8 wf0, wf1;
#pragma unroll
  for (int j = 0; j < 8; ++j) {
    if (arow < 4) {
      wf0[j] = f2bf(Wp[arow * 64 + 0  + kgrp * 8 + j]);
      wf1[j] = f2bf(Wp[arow * 64 + 32 + kgrp * 8 + j]);
    } else {
      wf0[j] = 0; wf1[j] = 0;
    }
  }
  const f32x4 zero = {0.f, 0.f, 0.f, 0.f};

  float4 a0, a1, a2, a3, b0, b1, b2, b3, c0, c1, c2, c3;  // 3-deep rotation
  LDSUB(a0, a1, a2, a3, 0);
  LDSUB(b0, b1, b2, b3, 1);
  LDSUB(c0, c1, c2, c3, 2);
  MFST(a0, a1, a2, a3, 0); LDSUB(a0, a1, a2, a3, 3);
  MFST(b0, b1, b2, b3, 1); LDSUB(b0, b1, b2, b3, 4);
  MFST(c0, c1, c2, c3, 2); LDSUB(c0, c1, c2, c3, 5);
  MFST(a0, a1, a2, a3, 3); LDSUB(a0, a1, a2, a3, 6);
  MFST(b0, b1, b2, b3, 4); LDSUB(b0, b1, b2, b3, 7);
  MFST(c0, c1, c2, c3, 5);
  MFST(a0, a1, a2, a3, 6);
  MFST(b0, b1, b2, b3, 7);
}

// ---- phase 2: elementwise tail, in-place on d_out ----
__global__ __launch_bounds__(256) void qtail_kernel(
    const float* __restrict__ bp,    // [4]
    const float4* __restrict__ Aws,  // [81] float4 (d_ws)
    float* __restrict__ io)          // [B][4] angles in, exps out
{
  const size_t idx = (size_t)blockIdx.x * 256 + threadIdx.x;
  float4* io4 = reinterpret_cast<float4*>(io);
  const float4 ang = io4[idx];

  const float t0 = 1.0f - 2.0f / (__expf(2.0f * (ang.x + bp[0])) + 1.0f);
  const float t1 = 1.0f - 2.0f / (__expf(2.0f * (ang.y + bp[1])) + 1.0f);
  const float t2 = 1.0f - 2.0f / (__expf(2.0f * (ang.z + bp[2])) + 1.0f);
  const float t3 = 1.0f - 2.0f / (__expf(2.0f * (ang.w + bp[3])) + 1.0f);

  float c0, s0, c1, s1, c2, s2, c3, s3;
  __sincosf(t0, &s0, &c0); __sincosf(t1, &s1, &c1);
  __sincosf(t2, &s2, &c2); __sincosf(t3, &s3, &c3);

  const float g[9] = {1.f, c1, s1, c0, c0 * c1, c0 * s1, s0, s0 * c1, s0 * s1};
  const float h[9] = {1.f, c3, s3, c2, c2 * c3, c2 * s3, s2, s2 * c3, s2 * s3};

  float e0 = 0.f, e1 = 0.f, e2 = 0.f, e3 = 0.f;
#pragma unroll
  for (int p = 0; p < 9; ++p) {
#pragma unroll
    for (int q = 0; q < 9; ++q) {
      const float4 a4 = Aws[p * 9 + q];   // uniform s_load, K$
      const float tt = g[p] * h[q];
      e0 = fmaf(a4.x, tt, e0); e1 = fmaf(a4.y, tt, e1);
      e2 = fmaf(a4.z, tt, e2); e3 = fmaf(a4.w, tt, e3);
    }
  }
  io4[idx] = make_float4(e0, e1, e2, e3);
}

extern "C" void kernel_launch(void* const* d_in, const int* in_sizes, int n_in,
                              void* d_out, int out_size, void* d_ws, size_t ws_size,
                              hipStream_t stream) {
  const float* x  = (const float*)d_in[0];
  const float* Wp = (const float*)d_in[1];
  const float* bp = (const float*)d_in[2];
  const float* qw = (const float*)d_in[3];
  float* out = (float*)d_out;
  float* A = (float*)d_ws;   // 324 floats
  (void)n_in; (void)out_size; (void)ws_size;

  qprep_kernel<<<1, 256, 0, stream>>>(qw, A);

  const int B = in_sizes[0] / 64;   // 524288 rows
  qgemv_kernel<<<B / 512, 256, 0, stream>>>(x, Wp, out);
  qtail_kernel<<<B / 256, 256, 0, stream>>>(bp, (const float4*)A, out);
}

// Round 17
// 35.810 us; speedup vs baseline: 1.2201x; 1.2201x over previous
//
#include <hip/hip_runtime.h>
#include <cmath>

// Round 17: r14's twice-proven MFMA qmain + full next-tile prefetch,
// with BOTH LDS hazards closed:
//   - WAR (TAIL(t) read vs tile t+1 write): LDS patch double-buffered
//     (wlds[wave][2][256]) -> reads and next writes touch different bytes.
//   - RAW (MFST writes -> TAIL read): explicit s_waitcnt lgkmcnt(0) +
//     sched_barrier(0) before the read (guide rule #18).
//   - Pipeline: 4 named buffer sets; after consuming each tile-0 subtile,
//     immediately reload it with tile-1's subtile -> all 256 B/lane of
//     tile 1 in flight during tile 0's ~1500cy tail (Little's-law fix).
//   - waves_per_eu(3,4): 168-VGPR budget (buffers ~64 + tail ~60), no spill.
//   - qprep split kernel verbatim (validated r10-r16).

typedef __attribute__((ext_vector_type(8))) short bf16x8;
typedef __attribute__((ext_vector_type(4))) float f32x4;

__device__ __forceinline__ short f2bf(float f) {
  const unsigned u = __float_as_uint(f);
  return (short)((u + 0x7FFF + ((u >> 16) & 1)) >> 16);   // RNE
}

// ---- prep kernel: verbatim round-10 (validated rounds 10-16) ----
__global__ __launch_bounds__(256) void qprep_kernel(
    const float* __restrict__ qw,   // [3][4][2]
    float* __restrict__ A_out)      // [81][4]
{
  __shared__ float sre[16][17];
  __shared__ float sim[16][17];
  __shared__ float M[4][16][16];
  const int tid = threadIdx.x;
  const int col = tid >> 4;
  const int u   = tid & 15;

  sre[col][u] = (u == col) ? 1.0f : 0.0f;
  sim[col][u] = 0.0f;
  __syncthreads();

#pragma unroll
  for (int l = 0; l < 3; ++l) {
#pragma unroll
    for (int w = 0; w < 4; ++w) {
      const int mask = 8 >> w;     // wire 0 = MSB
      float sh, ch, sh2, ch2;
      __sincosf(0.5f * qw[(l * 4 + w) * 2 + 0], &sh, &ch);    // RY
      __sincosf(0.5f * qw[(l * 4 + w) * 2 + 1], &sh2, &ch2);  // RZ
      const int ua = u & ~mask, ub = u | mask;
      const float ar = sre[col][ua], ai = sim[col][ua];
      const float br = sre[col][ub], bi = sim[col][ub];
      __syncthreads();
      float nr, ni;
      if (u & mask) { nr = sh * ar + ch * br; ni = sh * ai + ch * bi; }
      else          { nr = ch * ar - sh * br; ni = ch * ai - sh * bi; }
      float rr, ri;
      if (u & mask) { rr = ch2 * nr - sh2 * ni; ri = ch2 * ni + sh2 * nr; }
      else          { rr = ch2 * nr + sh2 * ni; ri = ch2 * ni - sh2 * nr; }
      sre[col][u] = rr; sim[col][u] = ri;
      __syncthreads();
    }
    int src = u;
    if (src & 1) src ^= 8;
    if (src & 2) src ^= 1;
    if (src & 4) src ^= 2;
    if (src & 8) src ^= 4;
    const float pr = sre[col][src], pi = sim[col][src];
    __syncthreads();
    sre[col][u] = pr; sim[col][u] = pi;
    __syncthreads();
  }

  for (int idx = tid; idx < 1024; idx += 256) {
    const int w = idx >> 8, s = (idx >> 4) & 15, t = idx & 15;
    const int mask = 8 >> w;
    float acc = 0.0f;
#pragma unroll
    for (int uu = 0; uu < 16; ++uu) {
      const float z = (uu & mask) ? -1.0f : 1.0f;
      acc += z * (sre[s][uu] * sre[t][uu] + sim[s][uu] * sim[t][uu]);
    }
    M[w][s][t] = acc;
  }
  __syncthreads();

  for (int idx = tid; idx < 324; idx += 256) {
    const int w = idx & 3, pq = idx >> 2;
    const int p = pq / 9, q = pq % 9;
    const int i0 = p / 3, i1 = p % 3, i2 = q / 3, i3 = q % 3;
    float acc = 0.0f;
#pragma unroll
    for (int comb = 0; comb < 16; ++comb) {
      int s = 0, t = 0;
      float coef = 0.0625f;
      int j;
      j = (comb >> 3) & 1; s |= j << 3; t |= ((i0 == 2) ? (j ^ 1) : j) << 3; if (i0 == 1 && j) coef = -coef;
      j = (comb >> 2) & 1; s |= j << 2; t |= ((i1 == 2) ? (j ^ 1) : j) << 2; if (i1 == 1 && j) coef = -coef;
      j = (comb >> 1) & 1; s |= j << 1; t |= ((i2 == 2) ? (j ^ 1) : j) << 1; if (i2 == 1 && j) coef = -coef;
      j = comb & 1;        s |= j;      t |= ((i3 == 2) ? (j ^ 1) : j);      if (i3 == 1 && j) coef = -coef;
      acc = fmaf(coef, M[w][s][t], acc);
    }
    A_out[idx] = acc;   // layout [pq*4 + w]
  }
}

// load subtile S (16 rows) of tile base R0 into 4 named float4 regs
#define LDSUB(V0, V1, V2, V3, R0, S) {                                      \
  const float* rp_ = x + ((R0) + (size_t)((S) * 16 + arow)) * 64 + kgrp * 8;\
  V0 = *reinterpret_cast<const float4*>(rp_);                               \
  V1 = *reinterpret_cast<const float4*>(rp_ + 4);                           \
  V2 = *reinterpret_cast<const float4*>(rp_ + 32);                          \
  V3 = *reinterpret_cast<const float4*>(rp_ + 36); }

// r14-proven: cvt + 2x MFMA (A=x, B=W^T) + scalar scatter into LDS buf LB
#define DOMFMA(V0, V1, V2, V3, M, LB) {                                     \
  bf16x8 af0_, af1_;                                                        \
  af0_[0] = f2bf(V0.x); af0_[1] = f2bf(V0.y); af0_[2] = f2bf(V0.z);         \
  af0_[3] = f2bf(V0.w); af0_[4] = f2bf(V1.x); af0_[5] = f2bf(V1.y);         \
  af0_[6] = f2bf(V1.z); af0_[7] = f2bf(V1.w);                               \
  af1_[0] = f2bf(V2.x); af1_[1] = f2bf(V2.y); af1_[2] = f2bf(V2.z);         \
  af1_[3] = f2bf(V2.w); af1_[4] = f2bf(V3.x); af1_[5] = f2bf(V3.y);         \
  af1_[6] = f2bf(V3.z); af1_[7] = f2bf(V3.w);                               \
  f32x4 acc_ = __builtin_amdgcn_mfma_f32_16x16x32_bf16(af0_, wf0, zero, 0, 0, 0); \
  acc_ = __builtin_amdgcn_mfma_f32_16x16x32_bf16(af1_, wf1, acc_, 0, 0, 0); \
  if (arow < 4) {                                                           \
    _Pragma("unroll")                                                       \
    for (int r_ = 0; r_ < 4; ++r_)                                          \
      myld[(LB) * 256 + ((M) * 16 + kgrp * 4 + r_) * 4 + arow] = acc_[r_];  \
  } }

// tail for one 64-row tile at base R0, reading LDS buffer LB
#define TAIL(R0, LB) {                                                      \
  asm volatile("s_waitcnt lgkmcnt(0)" ::: "memory");                        \
  __builtin_amdgcn_sched_barrier(0);                                        \
  const float4 ang =                                                        \
      *reinterpret_cast<const float4*>(&myld[(LB) * 256 + lane * 4]);       \
  const float t0 = 1.0f - 2.0f / (__expf(2.0f * (ang.x + bp[0])) + 1.0f);   \
  const float t1 = 1.0f - 2.0f / (__expf(2.0f * (ang.y + bp[1])) + 1.0f);   \
  const float t2 = 1.0f - 2.0f / (__expf(2.0f * (ang.z + bp[2])) + 1.0f);   \
  const float t3 = 1.0f - 2.0f / (__expf(2.0f * (ang.w + bp[3])) + 1.0f);   \
  float c0, s0, c1, s1, c2, s2, c3, s3;                                     \
  __sincosf(t0, &s0, &c0); __sincosf(t1, &s1, &c1);                         \
  __sincosf(t2, &s2, &c2); __sincosf(t3, &s3, &c3);                         \
  const float g[9] = {1.f, c1, s1, c0, c0 * c1, c0 * s1,                    \
                      s0, s0 * c1, s0 * s1};                                \
  const float h[9] = {1.f, c3, s3, c2, c2 * c3, c2 * s3,                    \
                      s2, s2 * c3, s2 * s3};                                \
  float e0 = 0.f, e1 = 0.f, e2 = 0.f, e3 = 0.f;                             \
  _Pragma("unroll")                                                         \
  for (int p_ = 0; p_ < 9; ++p_) {                                          \
    _Pragma("unroll")                                                       \
    for (int q_ = 0; q_ < 9; ++q_) {                                        \
      const float4 a4 = Aws[p_ * 9 + q_];                                   \
      const float tt = g[p_] * h[q_];                                       \
      e0 = fmaf(a4.x, tt, e0); e1 = fmaf(a4.y, tt, e1);                     \
      e2 = fmaf(a4.z, tt, e2); e3 = fmaf(a4.w, tt, e3);                     \
    }                                                                       \
  }                                                                         \
  reinterpret_cast<float4*>(out)[(R0) + lane] =                             \
      make_float4(e0, e1, e2, e3);                                          \
  asm volatile("" ::: "memory"); }

__global__ __launch_bounds__(256)
__attribute__((amdgpu_waves_per_eu(3, 4)))   // 168-VGPR budget: no spill
void qmain_kernel(
    const float* __restrict__ x,     // [B][64]
    const float* __restrict__ Wp,    // [4][64]
    const float* __restrict__ bp,    // [4]
    const float4* __restrict__ Aws,  // [81] float4 (d_ws)
    float* __restrict__ out)         // [B][4]
{
  __shared__ alignas(16) float wlds[4][2][256];   // 2KB/wave, double-buffered

  const int tid  = threadIdx.x;
  const int lane = tid & 63;
  const int wid  = tid >> 6;
  const int arow = lane & 15;        // x-row in subtile / C column (qubit)
  const int kgrp = lane >> 4;        // k-group
  float* myld = &wlds[wid][0][0];

  const size_t wrow0 = ((size_t)blockIdx.x * 4 + wid) * 128;  // 2 tiles

  // B fragment: W^T, cols 0..3 real, 4..15 zero (r13/r14-proven)
  bf16x8 wf0, wf1;
#pragma unroll
  for (int j = 0; j < 8; ++j) {
    if (arow < 4) {
      wf0[j] = f2bf(Wp[arow * 64 + 0  + kgrp * 8 + j]);
      wf1[j] = f2bf(Wp[arow * 64 + 32 + kgrp * 8 + j]);
    } else {
      wf0[j] = 0; wf1[j] = 0;
    }
  }
  const f32x4 zero = {0.f, 0.f, 0.f, 0.f};

  const size_t r0 = wrow0;            // tile 0
  const size_t r1 = wrow0 + 64;       // tile 1

  // four named buffer sets: full-tile pipeline depth
  float4 a0, a1, a2, a3, b0, b1, b2, b3;
  float4 c0, c1, c2, c3, d0, d1, d2, d3;

  // ---- tile 0: load 4 subtiles; each DOMFMA immediately reloads its
  //      buffer with tile 1's subtile (-> 256 B/lane in flight over tail)
  LDSUB(a0, a1, a2, a3, r0, 0);
  LDSUB(b0, b1, b2, b3, r0, 1);
  LDSUB(c0, c1, c2, c3, r0, 2);
  LDSUB(d0, d1, d2, d3, r0, 3);
  DOMFMA(a0, a1, a2, a3, 0, 0); LDSUB(a0, a1, a2, a3, r1, 0);
  DOMFMA(b0, b1, b2, b3, 1, 0); LDSUB(b0, b1, b2, b3, r1, 1);
  DOMFMA(c0, c1, c2, c3, 2, 0); LDSUB(c0, c1, c2, c3, r1, 2);
  DOMFMA(d0, d1, d2, d3, 3, 0); LDSUB(d0, d1, d2, d3, r1, 3);

  TAIL(r0, 0);   // reads buffer 0; tile-1 writes go to buffer 1 (no WAR)

  // ---- tile 1 ----
  DOMFMA(a0, a1, a2, a3, 0, 1);
  DOMFMA(b0, b1, b2, b3, 1, 1);
  DOMFMA(c0, c1, c2, c3, 2, 1);
  DOMFMA(d0, d1, d2, d3, 3, 1);

  TAIL(r1, 1);
}

extern "C" void kernel_launch(void* const* d_in, const int* in_sizes, int n_in,
                              void* d_out, int out_size, void* d_ws, size_t ws_size,
                              hipStream_t stream) {
  const float* x  = (const float*)d_in[0];
  const float* Wp = (const float*)d_in[1];
  const float* bp = (const float*)d_in[2];
  const float* qw = (const float*)d_in[3];
  float* out = (float*)d_out;
  float* A = (float*)d_ws;   // 324 floats
  (void)n_in; (void)out_size; (void)ws_size;

  qprep_kernel<<<1, 256, 0, stream>>>(qw, A);

  const int B = in_sizes[0] / 64;   // 524288 rows
  qmain_kernel<<<B / 512, 256, 0, stream>>>(x, Wp, bp,
                                            (const float4*)A, out);
}